// Round 8
// baseline (262.540 us; speedup 1.0000x reference)
//
#include <hip/hip_runtime.h>

// ---------------- problem constants ----------------
static constexpr int N_NODES = 100000;
static constexpr int N_EDGES = 3200000;
static constexpr int SHIFT  = 8;                          // 256 nodes / bucket
static constexpr int NPB    = 1 << SHIFT;                 // 256
static constexpr int NBK    = (N_NODES + NPB - 1) / NPB;  // 391 buckets
static constexpr int SLOTS  = NBK * NPB;                  // 100096
static constexpr int WGC    = 1024;                       // partition workgroups
static constexpr int CHUNK  = N_EDGES / WGC;              // 3125 edges / WG (exact)
static constexpr int PSPLIT = 4;                          // WGs per bucket in reduce

// record: .x = edge id, .y = src | (loc << 17)  (src < 2^17, loc < 256)

// ---- K1: per-WG histograms for both keys; transposed count matrices [NBK][WGC]
__global__ void __launch_bounds__(256) k_count(
    const int* __restrict__ row, const int* __restrict__ col,
    unsigned* __restrict__ cmC, unsigned* __restrict__ cmR)
{
    __shared__ unsigned hC[NBK], hR[NBK];
    for (int b = threadIdx.x; b < NBK; b += 256) { hC[b] = 0u; hR[b] = 0u; }
    __syncthreads();
    int w = blockIdx.x, e0 = w * CHUNK;
    for (int e = e0 + threadIdx.x; e < e0 + CHUNK; e += 256) {
        atomicAdd(&hC[col[e] >> SHIFT], 1u);
        atomicAdd(&hR[row[e] >> SHIFT], 1u);
    }
    __syncthreads();
    for (int b = threadIdx.x; b < NBK; b += 256) {
        cmC[(size_t)b * WGC + w] = hC[b];
        cmR[(size_t)b * WGC + w] = hR[b];
    }
}

// ---- K2: exclusive prefix over WGs per bucket (one warp per bucket row)
__global__ void __launch_bounds__(256) k_prefix(
    unsigned* __restrict__ cmC, unsigned* __restrict__ cmR,
    unsigned* __restrict__ totC, unsigned* __restrict__ totR)
{
    int warp = (blockIdx.x * 256 + threadIdx.x) >> 6;
    int lane = threadIdx.x & 63;
    if (warp >= 2 * NBK) return;
    unsigned* cm  = (warp < NBK) ? cmC : cmR;
    unsigned* tot = (warp < NBK) ? totC : totR;
    int b = (warp < NBK) ? warp : warp - NBK;
    unsigned* rowp = cm + (size_t)b * WGC;
    unsigned carry = 0;
    for (int base = 0; base < WGC; base += 64) {
        unsigned v = rowp[base + lane];
        unsigned inc = v;
        for (int off = 1; off < 64; off <<= 1) {
            unsigned t = __shfl_up(inc, off, 64);
            if (lane >= off) inc += t;
        }
        rowp[base + lane] = carry + inc - v;     // exclusive
        carry += __shfl(inc, 63, 64);
    }
    if (lane == 0) tot[b] = carry;
}

// ---- K3: exclusive scan of bucket totals -> bucket bases (blockIdx 0: col, 1: row)
__global__ void __launch_bounds__(256) k_scan(
    const unsigned* __restrict__ totC, const unsigned* __restrict__ totR,
    unsigned* __restrict__ baseC, unsigned* __restrict__ baseR)
{
    const unsigned* tot = blockIdx.x ? totR : totC;
    unsigned* base = blockIdx.x ? baseR : baseC;
    __shared__ unsigned tsum[256];
    int tid = threadIdx.x;
    unsigned a0 = (2 * tid     < NBK) ? tot[2 * tid]     : 0u;
    unsigned a1 = (2 * tid + 1 < NBK) ? tot[2 * tid + 1] : 0u;
    tsum[tid] = a0 + a1;
    __syncthreads();
    for (int off = 1; off < 256; off <<= 1) {
        unsigned v = (tid >= off) ? tsum[tid - off] : 0u;
        __syncthreads();
        tsum[tid] += v;
        __syncthreads();
    }
    unsigned ex = tid ? tsum[tid - 1] : 0u;
    if (2 * tid     < NBK) base[2 * tid]     = ex;
    if (2 * tid + 1 < NBK) base[2 * tid + 1] = ex + a0;
}

// ---- K4: partition edges into bucket-sorted records, LDS-staged coalesced writes
__global__ void __launch_bounds__(256) k_partition(
    const int* __restrict__ key,       // destination index per edge (col p1 / row p2)
    const int* __restrict__ pay,       // source index per edge      (row p1 / col p2)
    const unsigned* __restrict__ cm,   // prefix'd count matrix [NBK][WGC]
    const unsigned* __restrict__ base, // bucket bases [NBK]
    uint2* __restrict__ perm)
{
    __shared__ unsigned hist[NBK];
    __shared__ unsigned runstart[NBK + 1];
    __shared__ unsigned gdst[NBK];
    __shared__ unsigned tsum[256];
    __shared__ uint2 stage[CHUNK];          // 25 KB
    int w = blockIdx.x, tid = threadIdx.x, e0 = w * CHUNK;

    for (int b = tid; b < NBK; b += 256) {
        hist[b] = 0u;
        gdst[b] = base[b] + cm[(size_t)b * WGC + w];
    }
    __syncthreads();
    for (int e = e0 + tid; e < e0 + CHUNK; e += 256)
        atomicAdd(&hist[key[e] >> SHIFT], 1u);
    __syncthreads();
    unsigned a0 = (2 * tid     < NBK) ? hist[2 * tid]     : 0u;
    unsigned a1 = (2 * tid + 1 < NBK) ? hist[2 * tid + 1] : 0u;
    tsum[tid] = a0 + a1;
    __syncthreads();
    for (int off = 1; off < 256; off <<= 1) {
        unsigned v = (tid >= off) ? tsum[tid - off] : 0u;
        __syncthreads();
        tsum[tid] += v;
        __syncthreads();
    }
    unsigned ex = tid ? tsum[tid - 1] : 0u;
    if (2 * tid     <= NBK) runstart[2 * tid]     = ex;
    if (2 * tid + 1 <= NBK) runstart[2 * tid + 1] = ex + a0;
    __syncthreads();
    for (int b = tid; b < NBK; b += 256) hist[b] = runstart[b];
    __syncthreads();
    for (int e = e0 + tid; e < e0 + CHUNK; e += 256) {
        int k = key[e], p = pay[e];
        int b = k >> SHIFT;
        unsigned pos = atomicAdd(&hist[b], 1u);
        stage[pos] = make_uint2((unsigned)e,
                                (unsigned)p | ((unsigned)(k & (NPB - 1)) << 17));
    }
    __syncthreads();
    for (int s = tid; s < CHUNK; s += 256) {
        int lo = 0, hi = NBK;
        while (hi - lo > 1) {
            int mid = (lo + hi) >> 1;
            if (runstart[mid] <= (unsigned)s) lo = mid; else hi = mid;
        }
        perm[(size_t)gdst[lo] + (unsigned)s - runstart[lo]] = stage[s];
    }
}

// ---- K5: 4 lanes per record. Lane q of a group reads boo[e*4+q] (same 64B line)
//      -> 16 lines per wave-instruction instead of 64. Partials to per-sub buffer.
template<int TRANS>
__global__ void __launch_bounds__(512) k_reduce(
    const uint2* __restrict__ perm,
    const float4* __restrict__ vin,     // x (pass1) or lt (pass2)
    const float4* __restrict__ boo,
    const unsigned* __restrict__ base, const unsigned* __restrict__ tot,
    float4* __restrict__ part)          // [PSPLIT][SLOTS] partials
{
    __shared__ float acc[NPB][4];       // bank = (loc*4+q)%32: group -> 4 distinct banks
    int b = blockIdx.x / PSPLIT, sub = blockIdx.x % PSPLIT;
    int tid = threadIdx.x;
    for (int i = tid; i < NPB * 4; i += 512) ((float*)acc)[i] = 0.f;
    __syncthreads();
    unsigned start = base[b], n = tot[b];
    int g = tid >> 2;     // group 0..127
    int q = tid & 3;      // lane within group
    for (unsigned i = start + sub * 128 + g; i < start + n; i += 128 * PSPLIT) {
        uint2 rec = perm[i];                      // broadcast within group
        unsigned e   = rec.x;
        unsigned src = rec.y & 0x1FFFFu;
        unsigned loc = rec.y >> 17;
        float4 v  = vin[src];                     // shared line within group
        float4 ch = boo[(size_t)e * 4 + q];       // row q of A; group = one 64B line
        float mq;
        if (TRANS) {
            // m_i = sum_q v[q]*A[q][i]; lane q contributes v[q]*row_q, group-sum
            float vq = (q == 0) ? v.x : (q == 1) ? v.y : (q == 2) ? v.z : v.w;
            float p0 = vq * ch.x, p1 = vq * ch.y, p2 = vq * ch.z, p3 = vq * ch.w;
            p0 += __shfl_xor(p0, 1); p1 += __shfl_xor(p1, 1);
            p2 += __shfl_xor(p2, 1); p3 += __shfl_xor(p3, 1);
            p0 += __shfl_xor(p0, 2); p1 += __shfl_xor(p1, 2);
            p2 += __shfl_xor(p2, 2); p3 += __shfl_xor(p3, 2);
            mq = (q == 0) ? p0 : (q == 1) ? p1 : (q == 2) ? p2 : p3;
        } else {
            // m_q = dot(row_q, v)
            mq = ch.x * v.x + ch.y * v.y + ch.z * v.z + ch.w * v.w;
        }
        atomicAdd(&acc[loc][q], mq);
    }
    __syncthreads();
    for (int i = tid; i < NPB; i += 512) {
        part[(size_t)sub * SLOTS + (size_t)b * NPB + i] =
            make_float4(acc[i][0], acc[i][1], acc[i][2], acc[i][3]);
    }
}

// ---- K6: merge PSPLIT partial buffers -> final vector
__global__ void __launch_bounds__(256) k_merge(
    const float4* __restrict__ part, float4* __restrict__ vout)
{
    int s = blockIdx.x * 256 + threadIdx.x;
    if (s >= N_NODES) return;
    float4 r = part[s];
    for (int sub = 1; sub < PSPLIT; ++sub) {
        float4 t = part[(size_t)sub * SLOTS + s];
        r.x += t.x; r.y += t.y; r.z += t.z; r.w += t.w;
    }
    vout[s] = r;
}

// ================= fallback path (R3: sector-merged global atomics) =================

__global__ void __launch_bounds__(256) llt_pass1(
    const float* __restrict__ x, const int* __restrict__ row_idx,
    const int* __restrict__ col_idx, const float* __restrict__ boo,
    float* __restrict__ lt)
{
    int t = blockIdx.x * blockDim.x + threadIdx.x;
    if (t >= N_EDGES * 4) return;
    int e = t >> 2, i = t & 3;
    int r = row_idx[e], c = col_idx[e];
    const float* A = boo + (size_t)e * 16;
    const float* xv = x + (size_t)r * 4;
    float m = A[0*4+i]*xv[0] + A[1*4+i]*xv[1] + A[2*4+i]*xv[2] + A[3*4+i]*xv[3];
    atomicAdd(lt + (size_t)c * 4 + i, m);
}

__global__ void __launch_bounds__(256) llt_pass2(
    const float4* __restrict__ lt, const int* __restrict__ row_idx,
    const int* __restrict__ col_idx, const float4* __restrict__ boo,
    float* __restrict__ out)
{
    int t = blockIdx.x * blockDim.x + threadIdx.x;
    if (t >= N_EDGES * 4) return;
    int e = t >> 2, i = t & 3;
    int r = row_idx[e], c = col_idx[e];
    float4 arow = boo[(size_t)e * 4 + i];
    float4 lv = lt[c];
    float m = arow.x*lv.x + arow.y*lv.y + arow.z*lv.z + arow.w*lv.w;
    atomicAdd(out + (size_t)r * 4 + i, m);
}

// ================= host =================

extern "C" void kernel_launch(void* const* d_in, const int* in_sizes, int n_in,
                              void* d_out, int out_size, void* d_ws, size_t ws_size,
                              hipStream_t stream) {
    const float4* x = (const float4*)d_in[0];        // [100000,4] f32
    const int* edge_index = (const int*)d_in[1];     // [2, 3200000] int32
    const float4* boo = (const float4*)d_in[2];      // [3200000,4,4] f32
    const int* row = edge_index;                     // edge_index[0]
    const int* col = edge_index + N_EDGES;           // edge_index[1]
    float4* out = (float4*)d_out;

    auto align256 = [](size_t v) { return (v + 255) & ~(size_t)255; };
    const size_t sz_cm   = align256((size_t)NBK * WGC * 4);   // 1.6 MB each
    const size_t sz_vec  = align256((size_t)NBK * 4);
    const size_t sz_perm = align256((size_t)N_EDGES * 8);     // 25.6 MB (shared by passes)
    const size_t sz_lt   = align256((size_t)SLOTS * 16);      // 1.6 MB
    const size_t sz_part = align256((size_t)PSPLIT * SLOTS * 16); // 6.4 MB
    const size_t need = 2 * sz_cm + 4 * sz_vec + sz_perm + sz_lt + sz_part;

    if (ws_size >= need) {
        char* p = (char*)d_ws;
        unsigned* cmC   = (unsigned*)p; p += sz_cm;
        unsigned* cmR   = (unsigned*)p; p += sz_cm;
        unsigned* totC  = (unsigned*)p; p += sz_vec;
        unsigned* totR  = (unsigned*)p; p += sz_vec;
        unsigned* baseC = (unsigned*)p; p += sz_vec;
        unsigned* baseR = (unsigned*)p; p += sz_vec;
        uint2*    perm  = (uint2*)p;    p += sz_perm;
        float4*   lt    = (float4*)p;   p += sz_lt;
        float4*   part  = (float4*)p;   p += sz_part;

        k_count<<<WGC, 256, 0, stream>>>(row, col, cmC, cmR);
        k_prefix<<<(2 * NBK + 3) / 4, 256, 0, stream>>>(cmC, cmR, totC, totR);
        k_scan<<<2, 256, 0, stream>>>(totC, totR, baseC, baseR);
        // pass 1: bucket by col, src = row, lt = A^T-scatter result
        k_partition<<<WGC, 256, 0, stream>>>(col, row, cmC, baseC, perm);
        k_reduce<1><<<NBK * PSPLIT, 512, 0, stream>>>(perm, x, boo, baseC, totC, part);
        k_merge<<<(N_NODES + 255) / 256, 256, 0, stream>>>(part, lt);
        // pass 2: bucket by row, src = col (perm buffer reused)
        k_partition<<<WGC, 256, 0, stream>>>(row, col, cmR, baseR, perm);
        k_reduce<0><<<NBK * PSPLIT, 512, 0, stream>>>(perm, (const float4*)lt, boo, baseR, totR, part);
        k_merge<<<(N_NODES + 255) / 256, 256, 0, stream>>>(part, out);
    } else {
        // fallback: sector-merged atomics (R3, 328 us)
        float* ltf = (float*)d_ws;
        hipMemsetAsync(ltf, 0, (size_t)N_NODES * 4 * sizeof(float), stream);
        hipMemsetAsync(out, 0, (size_t)N_NODES * 4 * sizeof(float), stream);
        const int grid = (N_EDGES * 4 + 255) / 256;
        llt_pass1<<<grid, 256, 0, stream>>>((const float*)x, row, col, (const float*)boo, ltf);
        llt_pass2<<<grid, 256, 0, stream>>>((const float4*)ltf, row, col, boo, (float*)out);
    }
}